// Round 9
// baseline (125.118 us; speedup 1.0000x reference)
//
#include <hip/hip_runtime.h>

// RandomHingeFern — CALIBRATION ROUND: identical to R7/R8 structure but the
// fern kernel is launched 3x (idempotent). dur_us - baseline = 2 x fern cost.
// This resolves harness-fixed-cost vs kernel-cost attribution.

#define B_TOT  4096
#define CIN    512
#define O_TOT  1024
#define DEPTH  10
#define LEAVES 1024
#define BT     128
#define OTILE  16

typedef float vf4 __attribute__((ext_vector_type(4)));
typedef float vf2 __attribute__((ext_vector_type(2)));

// ---------------- Kernel 1: x -> xT (64x64 tiles via swizzled LDS) ----------
__global__ __launch_bounds__(256, 4) void transpose_kernel(
    const float* __restrict__ x,   // [B][CIN]
    float* __restrict__ xT)        // [CIN][B]
{
    __shared__ float tile[64 * 64];         // 16 KB, slot = r*64 + (c ^ r)
    const int t  = threadIdx.x;
    const int c0 = blockIdx.x * 64;         // channel tile (8)
    const int r0 = blockIdx.y * 64;         // batch tile  (64)

#pragma unroll
    for (int k = 0; k < 4; ++k) {
        const int id = k * 256 + t;         // 0..1023
        const int r  = id >> 4;             // 0..63
        const int c4 = id & 15;             // float4 col group
        const vf4 v = *reinterpret_cast<const vf4*>(
            x + (size_t)(r0 + r) * CIN + c0 + (c4 << 2));
        const int c = c4 << 2;
        tile[r * 64 + ((c + 0) ^ r)] = v.x;
        tile[r * 64 + ((c + 1) ^ r)] = v.y;
        tile[r * 64 + ((c + 2) ^ r)] = v.z;
        tile[r * 64 + ((c + 3) ^ r)] = v.w;
    }
    __syncthreads();

#pragma unroll
    for (int k = 0; k < 4; ++k) {
        const int id = k * 256 + t;
        const int c  = id >> 4;             // channel row of xT
        const int j4 = id & 15;             // b float4 group
        vf4 v;
        v.x = tile[(j4 * 4 + 0) * 64 + (c ^ (j4 * 4 + 0))];
        v.y = tile[(j4 * 4 + 1) * 64 + (c ^ (j4 * 4 + 1))];
        v.z = tile[(j4 * 4 + 2) * 64 + (c ^ (j4 * 4 + 2))];
        v.w = tile[(j4 * 4 + 3) * 64 + (c ^ (j4 * 4 + 3))];
        *reinterpret_cast<vf4*>(xT + (size_t)(c0 + c) * B_TOT + r0 + (j4 << 2)) = v;
    }
}

// ---------------- Kernel 2: fern (identical to R8) ----------------
__global__ __launch_bounds__(256, 4) void fern_kernel(
    const float* __restrict__ xT,         // [CIN][B]
    const float* __restrict__ thresholds, // [O][DEPTH]
    const int*   __restrict__ ordinals,   // [O][DEPTH]
    const float* __restrict__ weights,    // [O][LEAVES]
    float*       __restrict__ out)        // [B][O]
{
    __shared__ vf2 osh[OTILE * 64];       // 8 KB, [ol][bp ^ ol]

    const int t    = threadIdx.x;
    const int lane = t & 63;                                   // b-pair index
    const int wu   = __builtin_amdgcn_readfirstlane(t >> 6);   // wave 0..3

    const int id = blockIdx.x;            // 0..2047
    const int k  = id & 7;                // XCD under %8 round-robin
    const int j  = id >> 3;               // 0..255
    const int b0 = ((k & 3) * 8 + (j & 7)) * BT;
    const int o0 = ((k >> 2) * 32 + (j >> 3)) * OTILE;

#pragma unroll
    for (int i = 0; i < 4; ++i) {
        const int ol = wu * 4 + i;                  // wave-uniform
        const int o  = o0 + ol;
        const int*   op = ordinals   + o * DEPTH;   // SGPR base -> s_load
        const float* tp = thresholds + o * DEPTH;   // SGPR base -> s_load

        vf2 xv[DEPTH];
#pragma unroll
        for (int d = 0; d < DEPTH; ++d)
            xv[d] = *reinterpret_cast<const vf2*>(
                xT + (size_t)op[d] * B_TOT + b0 + 2 * lane);

        int   leaf0 = 0, leaf1 = 0;
        float mm0 = 1e30f, mm1 = 1e30f;
#pragma unroll
        for (int d = 0; d < DEPTH; ++d) {
            const float thr = tp[d];
            const float g0  = xv[d].x - thr;
            const float g1  = xv[d].y - thr;
            leaf0 = (leaf0 << 1) | (g0 > 0.0f ? 1 : 0);
            leaf1 = (leaf1 << 1) | (g1 > 0.0f ? 1 : 0);
            mm0   = fminf(mm0, fabsf(g0));
            mm1   = fminf(mm1, fabsf(g1));
        }
        const float* wrow = weights + (size_t)o * LEAVES;
        vf2 r;
        r.x = wrow[leaf0] * mm0;                    // same-row gathers
        r.y = wrow[leaf1] * mm1;
        osh[ol * 64 + (lane ^ ol)] = r;             // conflict-free b64 write
    }
    __syncthreads();

    const float* oshf = reinterpret_cast<const float*>(osh);
#pragma unroll
    for (int kk = 0; kk < 2; ++kk) {
        const int fid = kk * 256 + t;
        const int r   = fid >> 2;           // b row 0..127
        const int q   = (fid & 3) << 2;     // o col of .x
        vf4 v;
        v.x = oshf[((q + 0) * 64 + ((r >> 1) ^ (q + 0))) * 2 + (r & 1)];
        v.y = oshf[((q + 1) * 64 + ((r >> 1) ^ (q + 1))) * 2 + (r & 1)];
        v.z = oshf[((q + 2) * 64 + ((r >> 1) ^ (q + 2))) * 2 + (r & 1)];
        v.w = oshf[((q + 3) * 64 + ((r >> 1) ^ (q + 3))) * 2 + (r & 1)];
        __builtin_nontemporal_store(v, reinterpret_cast<vf4*>(
            out + (size_t)(b0 + r) * O_TOT + o0 + q));
    }
}

extern "C" void kernel_launch(void* const* d_in, const int* in_sizes, int n_in,
                              void* d_out, int out_size, void* d_ws, size_t ws_size,
                              hipStream_t stream) {
    const float* x          = (const float*)d_in[0];
    const float* thresholds = (const float*)d_in[1];
    const int*   ordinals   = (const int*)d_in[2];
    const float* weights    = (const float*)d_in[3];
    float*       out        = (float*)d_out;
    float*       xT         = (float*)d_ws;     // 8 MB

    dim3 tg(CIN / 64, B_TOT / 64);              // 8 x 64 = 512 blocks
    transpose_kernel<<<tg, 256, 0, stream>>>(x, xT);

    // CALIBRATION: 3x identical fern launches (idempotent).
    // dur_us - R8_baseline(89.7) = 2 x warm fern cost.
    fern_kernel<<<2048, 256, 0, stream>>>(xT, thresholds, ordinals, weights, out);
    fern_kernel<<<2048, 256, 0, stream>>>(xT, thresholds, ordinals, weights, out);
    fern_kernel<<<2048, 256, 0, stream>>>(xT, thresholds, ordinals, weights, out);
}

// Round 11
// 90.635 us; speedup vs baseline: 1.3804x; 1.3804x over previous
//
#include <hip/hip_runtime.h>

// RandomHingeFern: B=4096, C_in=512, O=1024, D=10, L=2^10=1024
// out[b,o] = weights[o, leaf(b,o)] * min_d |x[b, ord[o,d]] - thr[o,d]|
//
// Kernel 1: transpose x [B][CIN] -> xT [CIN][B] (d_ws, 8 MB).
// Kernel 2: fern. Block = (o-tile 16, b-range 512), 1024 threads (16 waves).
//   Weights rows staged in LDS (2 passes x 8 rows x 4KB) -> the random
//   per-lane leaf gather is a ds_read (no L2 line traffic). x loads are
//   coalesced vf2 from xT. Output staged in padded LDS, NT vf4 flush.
//   XCD swizzle: blockIdx%8 = b-range -> per-XCD 1MB x-slice L2-resident.

#define B_TOT  4096
#define CIN    512
#define O_TOT  1024
#define DEPTH  10
#define LEAVES 1024
#define OSH_LD 522    // padded row (floats): even (b64-aligned), 522%32=10 spreads banks

typedef float vf4 __attribute__((ext_vector_type(4)));
typedef float vf2 __attribute__((ext_vector_type(2)));

// ---------------- Kernel 1: x -> xT (64x64 tiles via swizzled LDS) ----------
__global__ __launch_bounds__(256, 4) void transpose_kernel(
    const float* __restrict__ x,   // [B][CIN]
    float* __restrict__ xT)        // [CIN][B]
{
    __shared__ float tile[64 * 64];         // 16 KB, slot = r*64 + (c ^ r)
    const int t  = threadIdx.x;
    const int c0 = blockIdx.x * 64;         // channel tile (8)
    const int r0 = blockIdx.y * 64;         // batch tile  (64)

#pragma unroll
    for (int k = 0; k < 4; ++k) {
        const int id = k * 256 + t;         // 0..1023
        const int r  = id >> 4;             // 0..63
        const int c4 = id & 15;             // float4 col group
        const vf4 v = *reinterpret_cast<const vf4*>(
            x + (size_t)(r0 + r) * CIN + c0 + (c4 << 2));
        const int c = c4 << 2;
        tile[r * 64 + ((c + 0) ^ r)] = v.x;
        tile[r * 64 + ((c + 1) ^ r)] = v.y;
        tile[r * 64 + ((c + 2) ^ r)] = v.z;
        tile[r * 64 + ((c + 3) ^ r)] = v.w;
    }
    __syncthreads();

#pragma unroll
    for (int k = 0; k < 4; ++k) {
        const int id = k * 256 + t;
        const int c  = id >> 4;             // channel row of xT
        const int j4 = id & 15;             // b float4 group
        vf4 v;
        v.x = tile[(j4 * 4 + 0) * 64 + (c ^ (j4 * 4 + 0))];
        v.y = tile[(j4 * 4 + 1) * 64 + (c ^ (j4 * 4 + 1))];
        v.z = tile[(j4 * 4 + 2) * 64 + (c ^ (j4 * 4 + 2))];
        v.w = tile[(j4 * 4 + 3) * 64 + (c ^ (j4 * 4 + 3))];
        *reinterpret_cast<vf4*>(xT + (size_t)(c0 + c) * B_TOT + r0 + (j4 << 2)) = v;
    }
}

// ---------------- Kernel 2: fern ----------------
// 512 blocks x 1024 threads. Block: b0 = (id%8)*512, o0 = (id/8)*16.
// Pass p in {0,1}: stage weights rows [o0+8p, o0+8p+8) into wlds (32 KB),
// then 16 waves x 2 tasks (task = o_idx*4 + b_chunk).
__global__ __launch_bounds__(1024, 4) void fern_kernel(
    const float* __restrict__ xT,         // [CIN][B]
    const float* __restrict__ thresholds, // [O][DEPTH]
    const int*   __restrict__ ordinals,   // [O][DEPTH]
    const float* __restrict__ weights,    // [O][LEAVES]
    float*       __restrict__ out)        // [B][O]
{
    __shared__ float wlds[8 * LEAVES];    // 32 KB
    __shared__ float osh[16 * OSH_LD];    // 33.4 KB, [o_loc][b + pad]

    const int t    = threadIdx.x;
    const int lane = t & 63;
    const int wv   = __builtin_amdgcn_readfirstlane(t >> 6);   // 0..15

    const int id = blockIdx.x;            // 0..511
    const int b0 = (id & 7) * 512;        // XCD %8 -> b-slice stays in that L2
    const int o0 = (id >> 3) * 16;

#pragma unroll
    for (int p = 0; p < 2; ++p) {
        // ---- stage 8 weight rows (32 KB), coalesced vf4, conflict-free
        const vf4* wsrc = reinterpret_cast<const vf4*>(
            weights + (size_t)(o0 + p * 8) * LEAVES);
        vf4* wdst = reinterpret_cast<vf4*>(wlds);
#pragma unroll
        for (int k = 0; k < 2; ++k)
            wdst[k * 1024 + t] = wsrc[k * 1024 + t];
        __syncthreads();

        // ---- compute: 32 tasks (8 o x 4 b-chunks), 2 per wave
#pragma unroll
        for (int q = 0; q < 2; ++q) {
            const int task = wv * 2 + q;         // 0..31, wave-uniform
            const int oi   = task >> 2;          // 0..7
            const int ch   = task & 3;           // 0..3
            const int o    = o0 + p * 8 + oi;
            const int*   op = ordinals   + o * DEPTH;   // SGPR -> s_load
            const float* tp = thresholds + o * DEPTH;   // SGPR -> s_load
            const int bb = b0 + ch * 128 + 2 * lane;

            vf2 xv[DEPTH];
#pragma unroll
            for (int d = 0; d < DEPTH; ++d)      // 10 coalesced 512B loads
                xv[d] = *reinterpret_cast<const vf2*>(
                    xT + (size_t)op[d] * B_TOT + bb);

            int   leaf0 = 0, leaf1 = 0;
            float mm0 = 1e30f, mm1 = 1e30f;
#pragma unroll
            for (int d = 0; d < DEPTH; ++d) {
                const float thr = tp[d];
                const float g0  = xv[d].x - thr;
                const float g1  = xv[d].y - thr;
                leaf0 = (leaf0 << 1) | (g0 > 0.0f ? 1 : 0);
                leaf1 = (leaf1 << 1) | (g1 > 0.0f ? 1 : 0);
                mm0   = fminf(mm0, fabsf(g0));
                mm1   = fminf(mm1, fabsf(g1));
            }
            vf2 r;
            r.x = wlds[oi * LEAVES + leaf0] * mm0;   // LDS gather (no L2)
            r.y = wlds[oi * LEAVES + leaf1] * mm1;
            *reinterpret_cast<vf2*>(
                &osh[(p * 8 + oi) * OSH_LD + ch * 128 + 2 * lane]) = r;
        }
        __syncthreads();
    }

    // ---- flush: 512 b x 16 o = 2048 vf4, 2 per thread, 64B-coalesced NT
#pragma unroll
    for (int k = 0; k < 2; ++k) {
        const int i  = k * 1024 + t;
        const int b  = i >> 2;               // 0..511
        const int oq = (i & 3) << 2;         // 0,4,8,12
        vf4 v;
        v.x = osh[(oq + 0) * OSH_LD + b];
        v.y = osh[(oq + 1) * OSH_LD + b];
        v.z = osh[(oq + 2) * OSH_LD + b];
        v.w = osh[(oq + 3) * OSH_LD + b];
        __builtin_nontemporal_store(v, reinterpret_cast<vf4*>(
            out + (size_t)(b0 + b) * O_TOT + o0 + oq));
    }
}

extern "C" void kernel_launch(void* const* d_in, const int* in_sizes, int n_in,
                              void* d_out, int out_size, void* d_ws, size_t ws_size,
                              hipStream_t stream) {
    const float* x          = (const float*)d_in[0];
    const float* thresholds = (const float*)d_in[1];
    const int*   ordinals   = (const int*)d_in[2];
    const float* weights    = (const float*)d_in[3];
    float*       out        = (float*)d_out;
    float*       xT         = (float*)d_ws;     // 8 MB

    dim3 tg(CIN / 64, B_TOT / 64);              // 8 x 64 = 512 blocks
    transpose_kernel<<<tg, 256, 0, stream>>>(x, xT);

    fern_kernel<<<512, 1024, 0, stream>>>(xT, thresholds, ordinals, weights, out);
}

// Round 14
// 86.333 us; speedup vs baseline: 1.4492x; 1.0498x over previous
//
#include <hip/hip_runtime.h>

// RandomHingeFern: B=4096, C_in=512, O=1024, D=10, L=2^10=1024
// out[b,o] = weights[o, leaf(b,o)] * min_d |x[b, ord[o,d]] - thr[o,d]|
//
// Kernel 1: transpose x [B][CIN] -> xT [CIN][B] (d_ws, 8 MB).
// Kernel 2: fern, vf4 b-pairing. lane handles 4 consecutive b (one vf4 load
//   per (o,d) -> 1024B/wave-instr, half the issue count of vf2). o wave-
//   uniform (scalar ord/thr loads). 4 same-row weights gathers per task.
//   XCD-rectangle swizzle: per-XCD 2MB x-slice + 2MB weights L2-resident.

#define B_TOT  4096
#define CIN    512
#define O_TOT  1024
#define DEPTH  10
#define LEAVES 1024
#define OSH_LD 268    // row stride (floats): mult of 4 (vf4-aligned), %32=12 -> ~2-way flush

typedef float vf4 __attribute__((ext_vector_type(4)));

// ---------------- Kernel 1: x -> xT (64x64 tiles via swizzled LDS) ----------
__global__ __launch_bounds__(256, 4) void transpose_kernel(
    const float* __restrict__ x,   // [B][CIN]
    float* __restrict__ xT)        // [CIN][B]
{
    __shared__ float tile[64 * 64];         // 16 KB, slot = r*64 + (c ^ r)
    const int t  = threadIdx.x;
    const int c0 = blockIdx.x * 64;         // channel tile (8)
    const int r0 = blockIdx.y * 64;         // batch tile  (64)

#pragma unroll
    for (int k = 0; k < 4; ++k) {
        const int id = k * 256 + t;         // 0..1023
        const int r  = id >> 4;             // 0..63
        const int c4 = id & 15;             // float4 col group
        const vf4 v = *reinterpret_cast<const vf4*>(
            x + (size_t)(r0 + r) * CIN + c0 + (c4 << 2));
        const int c = c4 << 2;
        tile[r * 64 + ((c + 0) ^ r)] = v.x;
        tile[r * 64 + ((c + 1) ^ r)] = v.y;
        tile[r * 64 + ((c + 2) ^ r)] = v.z;
        tile[r * 64 + ((c + 3) ^ r)] = v.w;
    }
    __syncthreads();

#pragma unroll
    for (int k = 0; k < 4; ++k) {
        const int id = k * 256 + t;
        const int c  = id >> 4;             // channel row of xT
        const int j4 = id & 15;             // b float4 group
        vf4 v;
        v.x = tile[(j4 * 4 + 0) * 64 + (c ^ (j4 * 4 + 0))];
        v.y = tile[(j4 * 4 + 1) * 64 + (c ^ (j4 * 4 + 1))];
        v.z = tile[(j4 * 4 + 2) * 64 + (c ^ (j4 * 4 + 2))];
        v.w = tile[(j4 * 4 + 3) * 64 + (c ^ (j4 * 4 + 3))];
        *reinterpret_cast<vf4*>(xT + (size_t)(c0 + c) * B_TOT + r0 + (j4 << 2)) = v;
    }
}

// ---------------- Kernel 2: fern (vf4 pairing) ----------------
// 1024 blocks x 256 threads (4 waves). b-tile 256 (4 b per lane), o-tile 16.
// XCD rectangle: k=id&7, j=id>>3; b_t=(k&3)*4+(j&3) in [0,16),
//                o_t=(k>>2)*32+(j>>2) in [0,64).
__global__ __launch_bounds__(256, 4) void fern_kernel(
    const float* __restrict__ xT,         // [CIN][B]
    const float* __restrict__ thresholds, // [O][DEPTH]
    const int*   __restrict__ ordinals,   // [O][DEPTH]
    const float* __restrict__ weights,    // [O][LEAVES]
    float*       __restrict__ out)        // [B][O]
{
    __shared__ float osh[16 * OSH_LD];    // 17.2 KB, [o_loc][4*lane..]

    const int t    = threadIdx.x;
    const int lane = t & 63;
    const int wv   = __builtin_amdgcn_readfirstlane(t >> 6);   // 0..3

    const int id = blockIdx.x;            // 0..1023
    const int k  = id & 7;                // XCD under %8 round-robin
    const int j  = id >> 3;               // 0..127
    const int b0 = ((k & 3) * 4 + (j & 3)) * 256;
    const int o0 = ((k >> 2) * 32 + (j >> 2)) * 16;
    const int bb = b0 + 4 * lane;

#pragma unroll
    for (int i = 0; i < 4; ++i) {
        const int ol = wv * 4 + i;                  // wave-uniform
        const int o  = o0 + ol;
        const int*   op = ordinals   + o * DEPTH;   // SGPR base -> s_load
        const float* tp = thresholds + o * DEPTH;   // SGPR base -> s_load

        // 10 coalesced 1024B vf4 loads, all issued up front (deep MLP).
        vf4 xv[DEPTH];
#pragma unroll
        for (int d = 0; d < DEPTH; ++d)
            xv[d] = *reinterpret_cast<const vf4*>(
                xT + (size_t)op[d] * B_TOT + bb);

        int   leaf[4] = {0, 0, 0, 0};
        float mm[4]   = {1e30f, 1e30f, 1e30f, 1e30f};
#pragma unroll
        for (int d = 0; d < DEPTH; ++d) {
            const float thr = tp[d];
#pragma unroll
            for (int u = 0; u < 4; ++u) {
                const float g = xv[d][u] - thr;
                leaf[u] = (leaf[u] << 1) | (g > 0.0f ? 1 : 0);
                mm[u]   = fminf(mm[u], fabsf(g));
            }
        }
        const float* wrow = weights + (size_t)o * LEAVES;
        vf4 r;
#pragma unroll
        for (int u = 0; u < 4; ++u)
            r[u] = wrow[leaf[u]] * mm[u];           // 4 same-row gathers (L1-hot)
        *reinterpret_cast<vf4*>(&osh[ol * OSH_LD + 4 * lane]) = r;
    }
    __syncthreads();

    // ---- flush: 256 b x 16 o = 1024 vf4, 4 per thread, 64B-coalesced NT
#pragma unroll
    for (int kk = 0; kk < 4; ++kk) {
        const int i  = kk * 256 + t;
        const int b  = i >> 2;               // 0..255
        const int oq = (i & 3) << 2;         // 0,4,8,12
        vf4 v;
        v.x = osh[(oq + 0) * OSH_LD + b];
        v.y = osh[(oq + 1) * OSH_LD + b];
        v.z = osh[(oq + 2) * OSH_LD + b];
        v.w = osh[(oq + 3) * OSH_LD + b];
        __builtin_nontemporal_store(v, reinterpret_cast<vf4*>(
            out + (size_t)(b0 + b) * O_TOT + o0 + oq));
    }
}

extern "C" void kernel_launch(void* const* d_in, const int* in_sizes, int n_in,
                              void* d_out, int out_size, void* d_ws, size_t ws_size,
                              hipStream_t stream) {
    const float* x          = (const float*)d_in[0];
    const float* thresholds = (const float*)d_in[1];
    const int*   ordinals   = (const int*)d_in[2];
    const float* weights    = (const float*)d_in[3];
    float*       out        = (float*)d_out;
    float*       xT         = (float*)d_ws;     // 8 MB

    dim3 tg(CIN / 64, B_TOT / 64);              // 8 x 64 = 512 blocks
    transpose_kernel<<<tg, 256, 0, stream>>>(x, xT);

    fern_kernel<<<1024, 256, 0, stream>>>(xT, thresholds, ordinals, weights, out);
}